// Round 15
// baseline (139.855 us; speedup 1.0000x reference)
//
#include <hip/hip_runtime.h>
#include <hip/hip_bf16.h>

typedef _Float16 f16_t;
typedef __attribute__((ext_vector_type(8))) _Float16 f16x8;
typedef __attribute__((ext_vector_type(4))) float f32x4;

#define LFENCE() asm volatile("" ::: "memory")

__device__ __forceinline__ f16x8 cvt8(const float* p) {
  float4 v0 = *(const float4*)p;
  float4 v1 = *(const float4*)(p + 4);
  f16x8 a;
  a[0] = (f16_t)v0.x; a[1] = (f16_t)v0.y; a[2] = (f16_t)v0.z; a[3] = (f16_t)v0.w;
  a[4] = (f16_t)v1.x; a[5] = (f16_t)v1.y; a[6] = (f16_t)v1.z; a[7] = (f16_t)v1.w;
  return a;
}

// ---------------------------------------------------------------------------
// prep (verified r6-r14, UNCHANGED): blocks 0..10 transpose+f16 weights
//   slots 0..7 = {wq_s,wk_s,wv_s,wq_c,wk_c,wv_c,wo_s,wo_c}^T [col][k],
//   8..10 = WgT [128 col][384 k]. Blocks 11,12: W2'=(WoS@Wg2)^T, W3'=(WoC@Wg3)^T.
// Block 13: bg' = bg + bos@Wg2 + boc@Wg3.
// ---------------------------------------------------------------------------
__global__ __launch_bounds__(256) void prep_kernel(
    const float* wq_s, const float* wk_s, const float* wv_s,
    const float* wq_c, const float* wk_c, const float* wv_c,
    const float* wo_s, const float* wo_c, const float* wg,
    const float* bos, const float* boc, const float* bgin,
    f16_t* WT, float* bgp)
{
  const int b = blockIdx.x;
  const int tid = threadIdx.x;
  if (b < 11) {
    __shared__ float t[128][129];
    const float* src; f16_t* dst; int ostride;
    switch (b) {
      case 0: src = wq_s; break; case 1: src = wk_s; break;
      case 2: src = wv_s; break; case 3: src = wq_c; break;
      case 4: src = wk_c; break; case 5: src = wv_c; break;
      case 6: src = wo_s; break; case 7: src = wo_c; break;
      default: src = wg + (size_t)(b - 8) * 16384; break;
    }
    if (b < 8) { dst = WT + (size_t)b * 16384; ostride = 128; }
    else       { dst = WT + 8 * 16384 + (b - 8) * 128; ostride = 384; }
#pragma unroll
    for (int i = 0; i < 64; ++i) {
      const int idx = tid + i * 256;
      t[idx & 127][idx >> 7] = src[idx];
    }
    __syncthreads();
#pragma unroll
    for (int i = 0; i < 64; ++i) {
      const int idx = tid + i * 256;
      const int c = idx >> 7, r = idx & 127;
      dst[(size_t)c * ostride + r] = (f16_t)t[c][r];
    }
  } else if (b < 13) {
    const int matsel = b - 11;
    const float* wo = matsel ? wo_c : wo_s;
    const int joff = 128 + matsel * 128;
    f16_t* dst = WT + (size_t)(11 + matsel) * 16384;
    const int wv = tid >> 6, ln = tid & 63, l15 = ln & 15, g = ln >> 4;
    f32x4 acc[2][8];
#pragma unroll
    for (int mm = 0; mm < 2; ++mm)
#pragma unroll
      for (int nt = 0; nt < 8; ++nt) acc[mm][nt] = (f32x4){0.f, 0.f, 0.f, 0.f};
#pragma unroll
    for (int kt = 0; kt < 4; ++kt) {
      f16x8 a[2];
#pragma unroll
      for (int mm = 0; mm < 2; ++mm) {
        const int crow = wv * 32 + mm * 16 + l15;
#pragma unroll
        for (int jj = 0; jj < 8; ++jj)
          a[mm][jj] = (f16_t)wg[(size_t)(joff + kt * 32 + g * 8 + jj) * 128 + crow];
      }
#pragma unroll
      for (int nt = 0; nt < 8; ++nt) {
        f16x8 bf = cvt8(wo + (size_t)(nt * 16 + l15) * 128 + kt * 32 + g * 8);
        acc[0][nt] = __builtin_amdgcn_mfma_f32_16x16x32_f16(a[0], bf, acc[0][nt], 0, 0, 0);
        acc[1][nt] = __builtin_amdgcn_mfma_f32_16x16x32_f16(a[1], bf, acc[1][nt], 0, 0, 0);
      }
    }
#pragma unroll
    for (int mm = 0; mm < 2; ++mm)
#pragma unroll
      for (int nt = 0; nt < 8; ++nt)
#pragma unroll
        for (int r = 0; r < 4; ++r) {
          const int c = wv * 32 + mm * 16 + g * 4 + r;
          dst[(size_t)c * 128 + nt * 16 + l15] = (f16_t)acc[mm][nt][r];
        }
  } else {
    if (tid < 128) {
      float acc = bgin[tid];
      for (int j = 0; j < 128; ++j)
        acc += bos[j] * wg[(size_t)(128 + j) * 128 + tid] +
               boc[j] * wg[(size_t)(256 + j) * 128 + tid];
      bgp[tid] = acc;
    }
  }
}

// ---------------------------------------------------------------------------
// Full-width per-wave GEMM (nt=8, r12-proven): afr (own 16 rows) @ W -> 128
// cols -> LDS, row-major swizzled or transposed ([col][row], for V^T).
// ---------------------------------------------------------------------------
template <bool TRANSP>
__device__ __forceinline__ void gemm8(
    const f16x8 afr[4], const f16_t* __restrict__ W, const float* __restrict__ bias,
    char* Ob, int l15, int g, int rg)
{
  f32x4 acc[8];
#pragma unroll
  for (int nt = 0; nt < 8; ++nt) acc[nt] = (f32x4){0.f, 0.f, 0.f, 0.f};
#pragma unroll
  for (int nt = 0; nt < 8; ++nt)
#pragma unroll
    for (int kt = 0; kt < 4; ++kt) {
      f16x8 b = *(const f16x8*)(W + (size_t)(nt * 16 + l15) * 128 + kt * 32 + g * 8);
      acc[nt] = __builtin_amdgcn_mfma_f32_16x16x32_f16(afr[kt], b, acc[nt], 0, 0, 0);
    }
#pragma unroll
  for (int nt = 0; nt < 8; ++nt) {
    const int col = nt * 16 + l15;
    const float bv = bias[col];
#pragma unroll
    for (int r = 0; r < 4; ++r) {
      const int row = rg * 16 + g * 4 + r;
      const f16_t v = (f16_t)(acc[nt][r] + bv);
      if (TRANSP)
        *(f16_t*)(Ob + col * 256 + ((row * 2) ^ ((col & 7) << 4))) = v;
      else
        *(f16_t*)(Ob + row * 256 + ((col * 2) ^ ((row & 7) << 4))) = v;
    }
  }
}

// ---------------------------------------------------------------------------
// Q-GEMM -> 8 per-head B-frags in regs (r12-proven): 2 passes through 2KB
// wave scratch. bq[h]: lane l15 = q, k = depth g*8+j (g<2), zero for g>=2.
// ---------------------------------------------------------------------------
__device__ __forceinline__ void gemmQ2(
    const f16x8 afr[4], const f16_t* __restrict__ W, const float* __restrict__ bias,
    char* scr, int l15, int g, f16x8 bq[8])
{
#pragma unroll
  for (int p = 0; p < 2; ++p) {
    LFENCE();
    f32x4 acc[4];
#pragma unroll
    for (int nt = 0; nt < 4; ++nt) acc[nt] = (f32x4){0.f, 0.f, 0.f, 0.f};
#pragma unroll
    for (int nt = 0; nt < 4; ++nt)
#pragma unroll
      for (int kt = 0; kt < 4; ++kt) {
        f16x8 b = *(const f16x8*)(W + (size_t)(p * 64 + nt * 16 + l15) * 128 + kt * 32 + g * 8);
        acc[nt] = __builtin_amdgcn_mfma_f32_16x16x32_f16(afr[kt], b, acc[nt], 0, 0, 0);
      }
#pragma unroll
    for (int nt = 0; nt < 4; ++nt) {
      const float bv = bias[p * 64 + nt * 16 + l15];
      const int dloc = nt * 16 + l15;  // 0..63
#pragma unroll
      for (int r = 0; r < 4; ++r) {
        const int qp = g * 4 + r;
        *(f16_t*)(scr + qp * 128 + ((dloc * 2) ^ ((qp & 7) << 4))) = (f16_t)(acc[nt][r] + bv);
      }
    }
    LFENCE();
#pragma unroll
    for (int h = 0; h < 4; ++h) {
      f16x8 z = {0, 0, 0, 0, 0, 0, 0, 0};
      bq[p * 4 + h] = (g < 2)
        ? *(const f16x8*)(scr + l15 * 128 + (((h * 16 + g * 8) * 2) ^ ((l15 & 7) << 4)))
        : z;
    }
  }
  LFENCE();
}

// ---------------------------------------------------------------------------
// battn4: grid 512 = (branch, batch); 512 thr = 8 waves; LDS 74KB -> 2 blk/CU.
// Wave rg owns rows rg*16..+16, ALL 8 heads (r12 structure). After attention
// the wave holds the complete att[16x128] tile in regs (oall[8], normalized)
// -> out-proj + gate GEMMs are wave-local (ph3): per kt, transpose 2 heads
// through wave scratch (gemmQ2 pattern) into A-frags, accumulate
//   accO += A*Wo,  accZ += A*W2'/W3'  (+ self: accZ += X*Wg1).
// Self emits OS(f16)+zSX(f32, +bg'); cross emits OC(f16)+zC(f32).
// ---------------------------------------------------------------------------
__global__ __launch_bounds__(512) void battn4_kernel(
    const float* __restrict__ Xs, const float* __restrict__ Xc,
    const int* __restrict__ adj, const int* __restrict__ mask_s,
    const int* __restrict__ mask_c, const f16_t* __restrict__ WT,
    const float* __restrict__ bq_s, const float* __restrict__ bk_s,
    const float* __restrict__ bv_s, const float* __restrict__ bq_c,
    const float* __restrict__ bk_c, const float* __restrict__ bv_c,
    const float* __restrict__ bos, const float* __restrict__ boc,
    const float* __restrict__ bgp,
    f16_t* __restrict__ OS, f16_t* __restrict__ OC,
    float* __restrict__ ZS, float* __restrict__ ZC)
{
  __shared__ __align__(16) char Kb[32768];   // K [128 rows][256B] swizzled
  __shared__ __align__(16) char Vtb[32768];  // V^T [128 d][256B] swizzled
  __shared__ __align__(16) char WS[16384];   // 8 x 2KB wave scratch

  const bool self = blockIdx.x < 256;
  const int bb = blockIdx.x & 255;   // self/cross pair shares XCD (256%8==0)
  const int tid = threadIdx.x;
  const int rg = tid >> 6, ln = tid & 63, l15 = ln & 15, g = ln >> 4;
  const int arow = rg * 16 + l15;
  char* scr = WS + rg * 2048;

  const f16_t* WQ = WT + (size_t)(self ? 0 : 3) * 16384;
  const f16_t* WK = WT + (size_t)(self ? 1 : 4) * 16384;
  const f16_t* WV = WT + (size_t)(self ? 2 : 5) * 16384;
  const f16_t* WO = WT + (size_t)(self ? 6 : 7) * 16384;
  const f16_t* WZ = WT + (size_t)(self ? 11 : 12) * 16384;
  const f16_t* Wg1 = WT + 8 * 16384;   // [col][384], k<128 = X part
  const float* bqv = self ? bq_s : bq_c;
  const float* bkv = self ? bk_s : bk_c;
  const float* bvv = self ? bv_s : bv_c;
  const float* XK  = self ? Xs : Xc;
  const int* mask  = self ? mask_s : mask_c;

  // masks via per-wave ballots (regs)
  unsigned mw[4];
  {
    unsigned long long m0 = __ballot(mask[bb * 128 + ln] != 0);
    unsigned long long m1 = __ballot(mask[bb * 128 + 64 + ln] != 0);
    mw[0] = (unsigned)m0; mw[1] = (unsigned)(m0 >> 32);
    mw[2] = (unsigned)m1; mw[3] = (unsigned)(m1 >> 32);
  }
  // adj bits -> regs (r12-proven)
  unsigned aw[4];
  if (self) {
    const int row = rg * 16 + (ln & 15);
    const int w = ln >> 4;
    const int4* ap = (const int4*)(adj + ((size_t)bb * 128 + row) * 128 + w * 32);
    unsigned word = 0;
#pragma unroll
    for (int i = 0; i < 8; ++i) {
      int4 a = ap[i];
      word |= ((a.x != 0 ? 1u : 0u) | (a.y != 0 ? 2u : 0u) |
               (a.z != 0 ? 4u : 0u) | (a.w != 0 ? 8u : 0u)) << (i * 4);
    }
#pragma unroll
    for (int w2 = 0; w2 < 4; ++w2)
      aw[w2] = (unsigned)__shfl((int)word, w2 * 16 + l15) & mw[w2];
  } else {
#pragma unroll
    for (int w2 = 0; w2 < 4; ++w2) aw[w2] = mw[w2];
  }

  // ---- ph1: K -> Kb, V^T -> Vtb, Q -> bq[8] regs (r12 verbatim) ----
  f16x8 bq[8];
  f16x8 afrK[4];
  {
#pragma unroll
    for (int kt = 0; kt < 4; ++kt)
      afrK[kt] = cvt8(XK + (size_t)bb * 16384 + arow * 128 + kt * 32 + g * 8);
    gemm8<false>(afrK, WK, bkv, Kb, l15, g, rg);
    gemm8<true >(afrK, WV, bvv, Vtb, l15, g, rg);
    f16x8 afrQ[4];
    if (self) {
#pragma unroll
      for (int kt = 0; kt < 4; ++kt) afrQ[kt] = afrK[kt];
    } else {
#pragma unroll
      for (int kt = 0; kt < 4; ++kt)
        afrQ[kt] = cvt8(Xs + (size_t)bb * 16384 + arow * 128 + kt * 32 + g * 8);
    }
    gemmQ2(afrQ, WQ, bqv, scr, l15, g, bq);
  }
  __syncthreads();  // the only block barrier

  // ---- ph2: attention, 8 heads (r12 chunked math verbatim); keep oall ----
  const f32x4 zero = (f32x4){0.f, 0.f, 0.f, 0.f};
  char* Pw = scr;
  f32x4 oall[8];
#pragma unroll
  for (int h = 0; h < 8; ++h) {
    const int d = h * 16 + l15;
    float psum = 0.f;
    f32x4 o = zero;
#pragma unroll
    for (int c = 0; c < 4; ++c) {
      f32x4 st[2];
#pragma unroll
      for (int hf = 0; hf < 2; ++hf) {
        const int krow = (c * 2 + hf) * 16 + l15;
        f16x8 ak = {0, 0, 0, 0, 0, 0, 0, 0};
        if (g < 2)
          ak = *(const f16x8*)(Kb + krow * 256 + (((h * 16 + g * 8) * 2) ^ ((krow & 7) << 4)));
        st[hf] = __builtin_amdgcn_mfma_f32_16x16x32_f16(ak, bq[h], zero, 0, 0, 0);
      }
#pragma unroll
      for (int hf = 0; hf < 2; ++hf) {
        union { f16_t hh[4]; unsigned long long u; } pk;
#pragma unroll
        for (int r = 0; r < 4; ++r) {
          const int k = (c * 2 + hf) * 16 + g * 4 + r;
          const float e = __expf(st[hf][r] * 0.25f - 4.f);
          const float p = ((aw[k >> 5] >> (k & 31)) & 1u) ? e : 0.f;
          psum += p;   // row-sum for q = l15
          pk.hh[r] = (f16_t)p;
        }
        *(unsigned long long*)(Pw + l15 * 80 + hf * 32 + g * 8) = pk.u;
      }
      LFENCE();
      union { unsigned long long u[2]; f16x8 v; } pa2;
      pa2.u[0] = *(const unsigned long long*)(Pw + l15 * 80 + g * 16);
      pa2.u[1] = *(const unsigned long long*)(Pw + l15 * 80 + g * 16 + 8);
      LFENCE();
      f16x8 vb = *(const f16x8*)(Vtb + d * 256 + (((c * 32 + g * 8) * 2) ^ ((d & 7) << 4)));
      o = __builtin_amdgcn_mfma_f32_16x16x32_f16(pa2.v, vb, o, 0, 0, 0);
    }
    psum += __shfl_xor(psum, 16);
    psum += __shfl_xor(psum, 32);
    const float inv = 1.f / psum;  // for q = l15
#pragma unroll
    for (int r = 0; r < 4; ++r) {
      const float invq = __shfl(inv, g * 4 + r);  // for q = g*4+r (PV D-layout)
      oall[h][r] = o[r] * invq;
    }
  }

  // ---- ph3: out-proj + gate GEMMs, wave-local ----
  f32x4 accO[8], accZ[8];
#pragma unroll
  for (int nt = 0; nt < 8; ++nt) { accO[nt] = zero; accZ[nt] = zero; }
#pragma unroll
  for (int kt = 0; kt < 4; ++kt) {
    // transpose heads 2kt, 2kt+1 (D-layout) -> scr -> A-frag (gemmQ2 pattern)
    LFENCE();
#pragma unroll
    for (int hh2 = 0; hh2 < 2; ++hh2) {
      const int h = kt * 2 + hh2;
#pragma unroll
      for (int r = 0; r < 4; ++r) {
        const int rowl = g * 4 + r;
        *(f16_t*)(scr + rowl * 80 + (hh2 * 16 + l15) * 2) = (f16_t)oall[h][r];
      }
    }
    LFENCE();
    f16x8 afrA = *(const f16x8*)(scr + l15 * 80 + g * 16);
    LFENCE();
    __builtin_amdgcn_s_setprio(1);
#pragma unroll
    for (int nt = 0; nt < 8; ++nt) {
      const size_t col = nt * 16 + l15;
      const size_t ko = kt * 32 + g * 8;
      f16x8 bO = *(const f16x8*)(WO + col * 128 + ko);
      f16x8 bZ = *(const f16x8*)(WZ + col * 128 + ko);
      accO[nt] = __builtin_amdgcn_mfma_f32_16x16x32_f16(afrA, bO, accO[nt], 0, 0, 0);
      accZ[nt] = __builtin_amdgcn_mfma_f32_16x16x32_f16(afrA, bZ, accZ[nt], 0, 0, 0);
      if (self) {
        f16x8 bG = *(const f16x8*)(Wg1 + col * 384 + ko);
        accZ[nt] = __builtin_amdgcn_mfma_f32_16x16x32_f16(afrK[kt], bG, accZ[nt], 0, 0, 0);
      }
    }
    __builtin_amdgcn_s_setprio(0);
  }

  // ---- epilogue: OS/zSX (self) or OC/zC (cross) ----
  const float* bo = self ? bos : boc;
  f16_t* Ob = self ? OS : OC;
  float* Zb = self ? ZS : ZC;
#pragma unroll
  for (int nt = 0; nt < 8; ++nt) {
    const int col = nt * 16 + l15;
    const float bv = bo[col];
    const float bz = self ? bgp[col] : 0.f;
#pragma unroll
    for (int r = 0; r < 4; ++r) {
      const int row = rg * 16 + g * 4 + r;
      const size_t off = (size_t)bb * 16384 + row * 128 + col;
      Ob[off] = (f16_t)(accO[nt][r] + bv);
      Zb[off] = accZ[nt][r] + bz;
    }
  }
}

// ---------------------------------------------------------------------------
// blend: out = (1-sigmoid(zSX+zC))*OS + sigmoid*OC. Elementwise, BW-bound.
// 8 elems/thread, grid 2048 x 256.
// ---------------------------------------------------------------------------
__global__ __launch_bounds__(256) void blend_kernel(
    const f16_t* __restrict__ OS, const f16_t* __restrict__ OC,
    const float* __restrict__ ZS, const float* __restrict__ ZC,
    float* __restrict__ OUT)
{
  const size_t base = ((size_t)blockIdx.x * 256 + threadIdx.x) * 8;
  f16x8 os = *(const f16x8*)(OS + base);
  f16x8 oc = *(const f16x8*)(OC + base);
  float4 zs0 = *(const float4*)(ZS + base);
  float4 zs1 = *(const float4*)(ZS + base + 4);
  float4 zc0 = *(const float4*)(ZC + base);
  float4 zc1 = *(const float4*)(ZC + base + 4);
  float z[8] = {zs0.x + zc0.x, zs0.y + zc0.y, zs0.z + zc0.z, zs0.w + zc0.w,
                zs1.x + zc1.x, zs1.y + zc1.y, zs1.z + zc1.z, zs1.w + zc1.w};
  float o[8];
#pragma unroll
  for (int j = 0; j < 8; ++j) {
    const float gv = 1.f / (1.f + __expf(-z[j]));
    o[j] = (1.f - gv) * (float)os[j] + gv * (float)oc[j];
  }
  *(float4*)(OUT + base) = (float4){o[0], o[1], o[2], o[3]};
  *(float4*)(OUT + base + 4) = (float4){o[4], o[5], o[6], o[7]};
}

// ---------------------------------------------------------------------------
extern "C" void kernel_launch(void* const* d_in, const int* in_sizes, int n_in,
                              void* d_out, int out_size, void* d_ws, size_t ws_size,
                              hipStream_t stream)
{
  const float* x_self  = (const float*)d_in[0];
  const int*   adj     = (const int*)d_in[1];
  const int*   mask_s  = (const int*)d_in[2];
  const float* x_cross = (const float*)d_in[3];
  const int*   mask_c  = (const int*)d_in[4];
  const float* wq_s = (const float*)d_in[5];
  const float* bq_s = (const float*)d_in[6];
  const float* wk_s = (const float*)d_in[7];
  const float* bk_s = (const float*)d_in[8];
  const float* wv_s = (const float*)d_in[9];
  const float* bv_s = (const float*)d_in[10];
  const float* wo_s = (const float*)d_in[11];
  const float* bo_s = (const float*)d_in[12];
  const float* wq_c = (const float*)d_in[13];
  const float* bq_c = (const float*)d_in[14];
  const float* wk_c = (const float*)d_in[15];
  const float* bk_c = (const float*)d_in[16];
  const float* wv_c = (const float*)d_in[17];
  const float* bv_c = (const float*)d_in[18];
  const float* wo_c = (const float*)d_in[19];
  const float* bo_c = (const float*)d_in[20];
  const float* wg   = (const float*)d_in[21];
  const float* bg   = (const float*)d_in[22];
  float* out = (float*)d_out;

  // ws: 13 f16 weight slots + bg'(f32) + OS/OC (f16) + ZS/ZC (f32). ~51MB.
  const size_t SZ = (size_t)256 * 128 * 128;
  f16_t* WT  = (f16_t*)d_ws;
  float* bgp = (float*)(WT + 13 * 16384);
  f16_t* OS = (f16_t*)(bgp + 128);
  f16_t* OC = OS + SZ;
  float* ZS = (float*)(OC + SZ);
  float* ZC = ZS + SZ;

  prep_kernel<<<14, 256, 0, stream>>>(wq_s, wk_s, wv_s, wq_c, wk_c, wv_c,
                                      wo_s, wo_c, wg, bo_s, bo_c, bg, WT, bgp);
  battn4_kernel<<<512, 512, 0, stream>>>(x_self, x_cross, adj, mask_s, mask_c, WT,
                                         bq_s, bk_s, bv_s, bq_c, bk_c, bv_c,
                                         bo_s, bo_c, bgp, OS, OC, ZS, ZC);
  blend_kernel<<<2048, 256, 0, stream>>>(OS, OC, ZS, ZC, out);
}